// Round 7
// baseline (189.127 us; speedup 1.0000x reference)
//
#include <hip/hip_runtime.h>
#include <hip/hip_bf16.h>
#include <cstddef>
#include <cstdint>

#define B_ 2
#define S_ 2048
#define E_ 1024
#define H_ 16
#define D_ 64
#define WIN_ 3

using bf16x8 = __attribute__((ext_vector_type(8))) short;   // 8 bf16 = 4 VGPRs
using f32x4  = __attribute__((ext_vector_type(4))) float;   // 16x16 MFMA C/D
using f32x16 = __attribute__((ext_vector_type(16))) float;  // 32x32 MFMA C/D

static __device__ __forceinline__ unsigned short f2bf(float f) {
    union { float f; unsigned int u; } c; c.f = f;
    unsigned int r = c.u + 0x7FFF + ((c.u >> 16) & 1);   // round-to-nearest-even
    return (unsigned short)(r >> 16);
}

static __device__ __forceinline__ void gload16(const void* g, void* l) {
    __builtin_amdgcn_global_load_lds(
        (const __attribute__((address_space(1))) void*)g,
        (__attribute__((address_space(3))) void*)l, 16, 0, 0);
}

// XOR-swizzled LDS index (shorts) for [row][chunk-of-8-shorts] tiles with
// 64-short rows: slot = chunk ^ (row & 7). Breaks the 128B-row bank aliasing
// while staying global_load_lds-compatible (lane*16B contiguous).
#define SWZ(row, c) ((((row) * 8) + ((c) ^ ((row) & 7))) * 8)

// ---------------------------------------------------------------------------
// fp32 -> bf16 cast: y=0: x (4M elems), y=1..3: Wq/Wk/Wv (1M each)
// ---------------------------------------------------------------------------
__global__ __launch_bounds__(256) void cast_kernel(
    const float* __restrict__ X,  const float* __restrict__ Wq,
    const float* __restrict__ Wk, const float* __restrict__ Wv,
    unsigned short* __restrict__ xb,  unsigned short* __restrict__ wqb,
    unsigned short* __restrict__ wkb, unsigned short* __restrict__ wvb)
{
    const float* src; unsigned short* dst; int n;
    switch (blockIdx.y) {
        case 0:  src = X;  dst = xb;  n = B_ * S_ * E_; break;
        case 1:  src = Wq; dst = wqb; n = E_ * E_;      break;
        case 2:  src = Wk; dst = wkb; n = E_ * E_;      break;
        default: src = Wv; dst = wvb; n = E_ * E_;      break;
    }
    int i = (blockIdx.x * 256 + threadIdx.x) * 8;
    if (i >= n) return;
    float4 a = *(const float4*)(src + i);
    float4 b = *(const float4*)(src + i + 4);
    ushort4 lo, hi;
    lo.x = f2bf(a.x); lo.y = f2bf(a.y); lo.z = f2bf(a.z); lo.w = f2bf(a.w);
    hi.x = f2bf(b.x); hi.y = f2bf(b.y); hi.z = f2bf(b.z); hi.w = f2bf(b.w);
    *(ushort4*)(dst + i)     = lo;
    *(ushort4*)(dst + i + 4) = hi;
}

// ---------------------------------------------------------------------------
// bf16 MFMA projection GEMM (m97 structure + swizzled LDS):
// C[i,j] = sum_k A[i,k]*B[j,k]; 128x128 tile, BK=64, 4 waves, 4x4 frags.
// z=0: A=x, B=Wq -> q bf16 [B,H,S,D] scaled 1/8
// z=1: A=x, B=Wk -> k bf16 [B,H,S,D]
// z=2: A=Wv, B=x (swapped) -> v bf16 [B,H,D,S] with coalesced stores
// ---------------------------------------------------------------------------
__global__ __launch_bounds__(256, 4) void gemm_kernel(
    const unsigned short* __restrict__ xb,
    const unsigned short* __restrict__ wqb, const unsigned short* __restrict__ wkb,
    const unsigned short* __restrict__ wvb,
    const float* __restrict__ bq, const float* __restrict__ bk,
    const float* __restrict__ bv,
    unsigned short* __restrict__ qb, unsigned short* __restrict__ kb,
    unsigned short* __restrict__ vb)
{
    constexpr int BM = 128, BK = 64;
    __shared__ unsigned short As[BM * BK];
    __shared__ unsigned short Bs[BM * BK];

    const int t    = threadIdx.x;
    const int lane = t & 63;
    const int w    = t >> 6;
    const int l15  = lane & 15;
    const int quad = lane >> 4;
    const int wm   = w & 1;
    const int wn   = w >> 1;
    const int m0   = blockIdx.x * BM;
    const int n0   = blockIdx.y * BM;
    const int z    = blockIdx.z;

    const unsigned short *Ab, *Bb; const float* bias; unsigned short* outp;
    int i0, j0; float sc = 1.0f;
    if (z == 0)      { Ab = xb;  Bb = wqb; bias = bq; outp = qb; i0 = m0; j0 = n0; sc = 0.125f; }
    else if (z == 1) { Ab = xb;  Bb = wkb; bias = bk; outp = kb; i0 = m0; j0 = n0; }
    else             { Ab = wvb; Bb = xb;  bias = bv; outp = vb; i0 = n0; j0 = m0; }

    const int lrow = lane >> 3;
    const int gch  = ((lane & 7) ^ (lrow & 7)) * 8;
    const int lsl  = (lane & 7) * 8;

    f32x4 acc[4][4];
    #pragma unroll
    for (int mt = 0; mt < 4; ++mt)
        #pragma unroll
        for (int nt = 0; nt < 4; ++nt)
            #pragma unroll
            for (int r = 0; r < 4; ++r) acc[mt][nt][r] = 0.f;

    for (int k0 = 0; k0 < E_; k0 += BK) {
        __syncthreads();
        #pragma unroll
        for (int is = 0; is < 4; ++is) {
            int r = (w * 4 + is) * 8 + lrow;
            gload16(Ab + (size_t)(i0 + r) * E_ + k0 + gch, &As[r * BK + lsl]);
            gload16(Bb + (size_t)(j0 + r) * E_ + k0 + gch, &Bs[r * BK + lsl]);
        }
        __syncthreads();

        #pragma unroll
        for (int ks = 0; ks < 2; ++ks) {
            bf16x8 af[4], bfr[4];
            #pragma unroll
            for (int mt = 0; mt < 4; ++mt)
                af[mt] = *(const bf16x8*)&As[SWZ(wm*64 + mt*16 + l15, ks*4 + quad)];
            #pragma unroll
            for (int nt = 0; nt < 4; ++nt)
                bfr[nt] = *(const bf16x8*)&Bs[SWZ(wn*64 + nt*16 + l15, ks*4 + quad)];
            #pragma unroll
            for (int mt = 0; mt < 4; ++mt)
                #pragma unroll
                for (int nt = 0; nt < 4; ++nt)
                    acc[mt][nt] = __builtin_amdgcn_mfma_f32_16x16x32_bf16(
                        af[mt], bfr[nt], acc[mt][nt], 0, 0, 0);
        }
    }

    if (z < 2) {
        float bj[4];
        #pragma unroll
        for (int nt = 0; nt < 4; ++nt) bj[nt] = bias[j0 + wn*64 + nt*16 + l15];
        #pragma unroll
        for (int mt = 0; mt < 4; ++mt) {
            #pragma unroll
            for (int r = 0; r < 4; ++r) {
                int i = i0 + wm*64 + mt*16 + quad*4 + r;
                int b = i >> 11, s = i & (S_ - 1);
                #pragma unroll
                for (int nt = 0; nt < 4; ++nt) {
                    int jj = j0 + wn*64 + nt*16 + l15;
                    int hh = jj >> 6, d = jj & 63;
                    outp[(((size_t)(b * H_ + hh) * S_) + s) * D_ + d] =
                        f2bf((acc[mt][nt][r] + bj[nt]) * sc);
                }
            }
        }
    } else {
        #pragma unroll
        for (int mt = 0; mt < 4; ++mt) {
            #pragma unroll
            for (int r = 0; r < 4; ++r) {
                int i = i0 + wm*64 + mt*16 + quad*4 + r;
                int hh = i >> 6, d = i & 63;
                float bi = bias[i];
                #pragma unroll
                for (int nt = 0; nt < 4; ++nt) {
                    int jj = j0 + wn*64 + nt*16 + l15;
                    int b = jj >> 11, s = jj & (S_ - 1);
                    outp[(((size_t)(b * H_ + hh) * D_) + d) * S_ + s] =
                        f2bf(acc[mt][nt][r] + bi);
                }
            }
        }
    }
}

// ---------------------------------------------------------------------------
// MFMA attention, 32x32x16 variant. Block = 512 threads = 8 waves:
// wave = (wq in 0..3: 32-query tile) x (wk in 0..1: 64-key half). TQ=128,
// TK=128 staged as two 64-key halves (Ks0/Ks1, Vt0/Vt1, R5-verified swizzle).
// Each wave: S^T = K.Q^T via mfma_32x32x16 (A: m=lane&31,k=(lane>>5)*8+j;
// C/D: col=lane&31, row=(reg&3)+8*(reg>>2)+4*(lane>>5)), exp+inverted-window
// mask, P (bf16, packed b64) -> wave-private LDS, O += P.V over its key half.
// Key halves merged once at the epilogue through LDS (Oex aliases Pq).
// Denominator from the SAME truncated p values (bias cancels exactly).
// XCD swizzle: bh = (j&7)*4 + (j>>7) keeps each XCD on 4 bh (L2-resident K/V).
// ---------------------------------------------------------------------------
__global__ __launch_bounds__(512, 4) void attn_kernel(
    const unsigned short* __restrict__ Q, const unsigned short* __restrict__ K,
    const unsigned short* __restrict__ V, float* __restrict__ out)
{
    __shared__ unsigned short Ks0[4096], Ks1[4096];   // 8 KB each, [key][d] swizzled
    __shared__ unsigned short Vt0[4096], Vt1[4096];   // 8 KB each, [d][key] swizzled
    __shared__ unsigned short Pq[16384];              // 32 KB, 8 x wave-private 32x64
    __shared__ float          Dex[256];               // denom exchange

    const int t    = threadIdx.x;
    const int lane = t & 63;
    const int w    = t >> 6;        // wave 0..7
    const int wq   = w & 3;         // q-tile (32 rows)
    const int wk   = w >> 2;        // key half (64 keys)
    const int l31  = lane & 31;
    const int h    = lane >> 5;     // half-wave

    const int j   = blockIdx.x;
    const int bh  = (j & 7) * 4 + (j >> 7);
    const int q0  = ((j >> 3) & 15) * 128;
    const int wq0 = q0 + wq * 32;

    const unsigned short* Qp = Q + (size_t)bh * S_ * D_;
    const unsigned short* Kp = K + (size_t)bh * S_ * D_;
    const unsigned short* Vp = V + (size_t)bh * D_ * S_;   // [d][s]

    // Q B-operand frags (n = q = l31, k = ks*16 + h*8 + j), in regs all kernel
    bf16x8 qf[4];
    #pragma unroll
    for (int ks = 0; ks < 4; ++ks)
        qf[ks] = *(const bf16x8*)(Qp + (size_t)(wq0 + l31) * D_ + ks*16 + h*8);

    f32x16 Oacc[2];
    #pragma unroll
    for (int nt = 0; nt < 2; ++nt)
        #pragma unroll
        for (int r = 0; r < 16; ++r) Oacc[nt][r] = 0.f;
    float dsum = 0.f;   // denom partial for q = wq0 + l31 over this key half

    // staging (swizzle-inverse on global side); each wave fills 1KB per array
    const int lrow = lane >> 3;
    const int gch  = ((lane & 7) ^ lrow) * 8;
    const int srow = w * 8 + lrow;                    // 0..63
    const unsigned short* kg0 = Kp + (size_t)srow * D_ + gch;
    const unsigned short* kg1 = Kp + (size_t)(srow + 64) * D_ + gch;
    const unsigned short* vg0 = Vp + (size_t)srow * S_ + gch;
    const unsigned short* vg1 = Vp + (size_t)srow * S_ + 64 + gch;

    const unsigned short* KsW = wk ? Ks1 : Ks0;
    const unsigned short* VtW = wk ? Vt1 : Vt0;
    unsigned short* Pw = &Pq[w * 2048];               // wave-private 32q x 64k
    const int swz = (l31 & 7) << 1;                   // P chunk swizzle key

    for (int k0 = 0; k0 < S_; k0 += 128) {
        __syncthreads();                 // prior iter done reading Ks/Vt
        gload16(kg0, &Ks0[t * 8]);
        gload16(kg1, &Ks1[t * 8]);
        gload16(vg0, &Vt0[t * 8]);
        gload16(vg1, &Vt1[t * 8]);
        kg0 += 128 * D_; kg1 += 128 * D_; vg0 += 128; vg1 += 128;
        __syncthreads();                 // staged

        // ---- S^T = K Q^T : 64 keys (2 mt of 32) x 32 q per wave ----
        f32x16 sacc[2];
        #pragma unroll
        for (int mt = 0; mt < 2; ++mt)
            #pragma unroll
            for (int r = 0; r < 16; ++r) sacc[mt][r] = 0.f;
        #pragma unroll
        for (int mt = 0; mt < 2; ++mt)
            #pragma unroll
            for (int ks = 0; ks < 4; ++ks) {
                bf16x8 kf = *(const bf16x8*)&KsW[SWZ(mt*32 + l31, ks*2 + h)];
                sacc[mt] = __builtin_amdgcn_mfma_f32_32x32x16_bf16(
                    kf, qf[ks], sacc[mt], 0, 0, 0);
            }

        // ---- exp + (rare) inverted-window mask; packed b64 P writes ----
        #pragma unroll
        for (int mt = 0; mt < 2; ++mt) {
            const int kt0 = k0 + wk*64 + mt*32;
            const bool band = (unsigned)(wq0 - kt0 + 34) <= 68u;  // wave-uniform
            #pragma unroll
            for (int g = 0; g < 4; ++g) {
                union { unsigned short s[4]; unsigned long long u; } pk;
                #pragma unroll
                for (int r = 0; r < 4; ++r) {
                    float p;
                    if (band) {
                        int dlt = (wq0 + l31) - (kt0 + g*8 + h*4 + r);
                        if (dlt < 0) dlt = -dlt;
                        p = (dlt <= WIN_) ? 0.f : __expf(sacc[mt][g*4 + r]);
                    } else {
                        p = __expf(sacc[mt][g*4 + r]);
                    }
                    union { float f; unsigned int u; } c; c.f = p;
                    c.u &= 0xFFFF0000u;                  // bf16-representable
                    dsum += c.f;
                    pk.s[r] = (unsigned short)(c.u >> 16);
                }
                const int slot = (mt*8 + g*2 + h) ^ swz;
                *(unsigned long long*)&Pw[l31 * 64 + slot * 4] = pk.u;
            }
        }
        // no barrier: P region is wave-private

        // ---- O += P V over this wave's key half ----
        #pragma unroll
        for (int ks = 0; ks < 4; ++ks) {
            const int phys = (ks*4 + h*2) ^ swz;       // even -> 16B aligned
            bf16x8 pf = *(const bf16x8*)&Pw[l31 * 64 + phys * 4];
            #pragma unroll
            for (int nt = 0; nt < 2; ++nt) {
                bf16x8 vf = *(const bf16x8*)&VtW[SWZ(nt*32 + l31, ks*2 + h)];
                Oacc[nt] = __builtin_amdgcn_mfma_f32_32x32x16_bf16(
                    pf, vf, Oacc[nt], 0, 0, 0);
            }
        }
    }

    // ---- merge key halves: denom + O exchange through LDS ----
    dsum += __shfl_xor(dsum, 32);        // full 32-key-row coverage per q
    if (lane < 32) Dex[wk * 128 + wq * 32 + l31] = dsum;
    __syncthreads();                     // all Pq reads done; Dex visible
    float* Oex = (float*)Pq;             // alias P buffer (32 KB = 8192 floats)
    if (wk == 1) {
        #pragma unroll
        for (int nt = 0; nt < 2; ++nt)
            #pragma unroll
            for (int r = 0; r < 16; ++r)
                Oex[((wq*2 + nt)*16 + r)*64 + lane] = Oacc[nt][r];
    }
    __syncthreads();                     // Oex visible
    if (wk == 0) {
        const int b  = bh >> 4;
        const int hh = bh & 15;
        #pragma unroll
        for (int r = 0; r < 16; ++r) {
            const int qrow = (r & 3) + 8*(r >> 2) + 4*h;
            const float iv = 1.f / (Dex[wq*32 + qrow] + Dex[128 + wq*32 + qrow]);
            const int qg = wq0 + qrow;
            float* op = out + (((size_t)b * S_ + qg) * H_ + hh) * D_;
            #pragma unroll
            for (int nt = 0; nt < 2; ++nt)
                op[nt*32 + l31] =
                    (Oacc[nt][r] + Oex[((wq*2 + nt)*16 + r)*64 + lane]) * iv;
        }
    }
}

extern "C" void kernel_launch(void* const* d_in, const int* in_sizes, int n_in,
                              void* d_out, int out_size, void* d_ws, size_t ws_size,
                              hipStream_t stream) {
    const float* x  = (const float*)d_in[0];
    const float* Wq = (const float*)d_in[1];
    const float* bq = (const float*)d_in[2];
    const float* Wk = (const float*)d_in[3];
    const float* bk = (const float*)d_in[4];
    const float* Wv = (const float*)d_in[5];
    const float* bv = (const float*)d_in[6];
    float* out = (float*)d_out;

    const size_t per = (size_t)B_ * H_ * S_ * D_;   // 4,194,304 elements
    const size_t wsz = (size_t)E_ * E_;             // 1,048,576
    unsigned short* qb  = (unsigned short*)d_ws;
    unsigned short* kb  = qb + per;
    unsigned short* vb  = kb + per;
    unsigned short* xbf = vb + per;
    unsigned short* wqb = xbf + per;
    unsigned short* wkb = wqb + wsz;
    unsigned short* wvb = wkb + wsz;

    dim3 cgrid((B_ * S_ * E_ + 2047) / 2048, 4);
    cast_kernel<<<cgrid, 256, 0, stream>>>(x, Wq, Wk, Wv, xbf, wqb, wkb, wvb);

    dim3 ggrid(B_ * S_ / 128, E_ / 128, 3);
    gemm_kernel<<<ggrid, 256, 0, stream>>>(xbf, wqb, wkb, wvb, bq, bk, bv, qb, kb, vb);

    attn_kernel<<<dim3(512), 512, 0, stream>>>(qb, kb, vb, out);
}

// Round 8
// 178.207 us; speedup vs baseline: 1.0613x; 1.0613x over previous
//
#include <hip/hip_runtime.h>
#include <hip/hip_bf16.h>
#include <cstddef>
#include <cstdint>

#define B_ 2
#define S_ 2048
#define E_ 1024
#define H_ 16
#define D_ 64
#define WIN_ 3

using bf16x8 = __attribute__((ext_vector_type(8))) short;  // 8 bf16 = 4 VGPRs
using f32x4  = __attribute__((ext_vector_type(4))) float;  // MFMA C/D

static __device__ __forceinline__ unsigned short f2bf(float f) {
    union { float f; unsigned int u; } c; c.f = f;
    unsigned int r = c.u + 0x7FFF + ((c.u >> 16) & 1);   // round-to-nearest-even
    return (unsigned short)(r >> 16);
}

static __device__ __forceinline__ void gload16(const void* g, void* l) {
    __builtin_amdgcn_global_load_lds(
        (const __attribute__((address_space(1))) void*)g,
        (__attribute__((address_space(3))) void*)l, 16, 0, 0);
}

// XOR-swizzled LDS index (shorts) for [row][chunk-of-8-shorts] tiles with
// 64-short rows: slot = chunk ^ (row & 7). Breaks the 128B-row bank aliasing
// while staying global_load_lds-compatible (lane*16B contiguous).
#define SWZ(row, c) ((((row) * 8) + ((c) ^ ((row) & 7))) * 8)

// ---------------------------------------------------------------------------
// fp32 -> bf16 cast: y=0: x (4M elems), y=1..3: Wq/Wk/Wv (1M each)
// ---------------------------------------------------------------------------
__global__ __launch_bounds__(256) void cast_kernel(
    const float* __restrict__ X,  const float* __restrict__ Wq,
    const float* __restrict__ Wk, const float* __restrict__ Wv,
    unsigned short* __restrict__ xb,  unsigned short* __restrict__ wqb,
    unsigned short* __restrict__ wkb, unsigned short* __restrict__ wvb)
{
    const float* src; unsigned short* dst; int n;
    switch (blockIdx.y) {
        case 0:  src = X;  dst = xb;  n = B_ * S_ * E_; break;
        case 1:  src = Wq; dst = wqb; n = E_ * E_;      break;
        case 2:  src = Wk; dst = wkb; n = E_ * E_;      break;
        default: src = Wv; dst = wvb; n = E_ * E_;      break;
    }
    int i = (blockIdx.x * 256 + threadIdx.x) * 8;
    if (i >= n) return;
    float4 a = *(const float4*)(src + i);
    float4 b = *(const float4*)(src + i + 4);
    ushort4 lo, hi;
    lo.x = f2bf(a.x); lo.y = f2bf(a.y); lo.z = f2bf(a.z); lo.w = f2bf(a.w);
    hi.x = f2bf(b.x); hi.y = f2bf(b.y); hi.z = f2bf(b.z); hi.w = f2bf(b.w);
    *(ushort4*)(dst + i)     = lo;
    *(ushort4*)(dst + i + 4) = hi;
}

// ---------------------------------------------------------------------------
// bf16 MFMA projection GEMM (m97 structure + swizzled LDS):
// C[i,j] = sum_k A[i,k]*B[j,k]; 128x128 tile, BK=64, 4 waves, 4x4 frags.
// z=0: A=x, B=Wq -> q bf16 [B,H,S,D] scaled log2(e)/8 (exp2 softmax path)
// z=1: A=x, B=Wk -> k bf16 [B,H,S,D]
// z=2: A=Wv, B=x (swapped) -> v bf16 [B,H,D,S] with coalesced stores
// ---------------------------------------------------------------------------
__global__ __launch_bounds__(256, 4) void gemm_kernel(
    const unsigned short* __restrict__ xb,
    const unsigned short* __restrict__ wqb, const unsigned short* __restrict__ wkb,
    const unsigned short* __restrict__ wvb,
    const float* __restrict__ bq, const float* __restrict__ bk,
    const float* __restrict__ bv,
    unsigned short* __restrict__ qb, unsigned short* __restrict__ kb,
    unsigned short* __restrict__ vb)
{
    constexpr int BM = 128, BK = 64;
    __shared__ unsigned short As[BM * BK];
    __shared__ unsigned short Bs[BM * BK];

    const int t    = threadIdx.x;
    const int lane = t & 63;
    const int w    = t >> 6;
    const int l15  = lane & 15;
    const int quad = lane >> 4;
    const int wm   = w & 1;
    const int wn   = w >> 1;
    const int m0   = blockIdx.x * BM;
    const int n0   = blockIdx.y * BM;
    const int z    = blockIdx.z;

    const unsigned short *Ab, *Bb; const float* bias; unsigned short* outp;
    int i0, j0; float sc = 1.0f;
    if (z == 0)      { Ab = xb;  Bb = wqb; bias = bq; outp = qb; i0 = m0; j0 = n0;
                       sc = 0.125f * 1.44269504088896f; }
    else if (z == 1) { Ab = xb;  Bb = wkb; bias = bk; outp = kb; i0 = m0; j0 = n0; }
    else             { Ab = wvb; Bb = xb;  bias = bv; outp = vb; i0 = n0; j0 = m0; }

    const int lrow = lane >> 3;
    const int gch  = ((lane & 7) ^ (lrow & 7)) * 8;
    const int lsl  = (lane & 7) * 8;

    f32x4 acc[4][4];
    #pragma unroll
    for (int mt = 0; mt < 4; ++mt)
        #pragma unroll
        for (int nt = 0; nt < 4; ++nt)
            #pragma unroll
            for (int r = 0; r < 4; ++r) acc[mt][nt][r] = 0.f;

    for (int k0 = 0; k0 < E_; k0 += BK) {
        __syncthreads();
        #pragma unroll
        for (int is = 0; is < 4; ++is) {
            int r = (w * 4 + is) * 8 + lrow;
            gload16(Ab + (size_t)(i0 + r) * E_ + k0 + gch, &As[r * BK + lsl]);
            gload16(Bb + (size_t)(j0 + r) * E_ + k0 + gch, &Bs[r * BK + lsl]);
        }
        __syncthreads();

        #pragma unroll
        for (int ks = 0; ks < 2; ++ks) {
            bf16x8 af[4], bfr[4];
            #pragma unroll
            for (int mt = 0; mt < 4; ++mt)
                af[mt] = *(const bf16x8*)&As[SWZ(wm*64 + mt*16 + l15, ks*4 + quad)];
            #pragma unroll
            for (int nt = 0; nt < 4; ++nt)
                bfr[nt] = *(const bf16x8*)&Bs[SWZ(wn*64 + nt*16 + l15, ks*4 + quad)];
            #pragma unroll
            for (int mt = 0; mt < 4; ++mt)
                #pragma unroll
                for (int nt = 0; nt < 4; ++nt)
                    acc[mt][nt] = __builtin_amdgcn_mfma_f32_16x16x32_bf16(
                        af[mt], bfr[nt], acc[mt][nt], 0, 0, 0);
        }
    }

    if (z < 2) {
        float bj[4];
        #pragma unroll
        for (int nt = 0; nt < 4; ++nt) bj[nt] = bias[j0 + wn*64 + nt*16 + l15];
        #pragma unroll
        for (int mt = 0; mt < 4; ++mt) {
            #pragma unroll
            for (int r = 0; r < 4; ++r) {
                int i = i0 + wm*64 + mt*16 + quad*4 + r;
                int b = i >> 11, s = i & (S_ - 1);
                #pragma unroll
                for (int nt = 0; nt < 4; ++nt) {
                    int jj = j0 + wn*64 + nt*16 + l15;
                    int hh = jj >> 6, d = jj & 63;
                    outp[(((size_t)(b * H_ + hh) * S_) + s) * D_ + d] =
                        f2bf((acc[mt][nt][r] + bj[nt]) * sc);
                }
            }
        }
    } else {
        #pragma unroll
        for (int mt = 0; mt < 4; ++mt) {
            #pragma unroll
            for (int r = 0; r < 4; ++r) {
                int i = i0 + wm*64 + mt*16 + quad*4 + r;
                int hh = i >> 6, d = i & 63;
                float bi = bias[i];
                #pragma unroll
                for (int nt = 0; nt < 4; ++nt) {
                    int jj = j0 + wn*64 + nt*16 + l15;
                    int b = jj >> 11, s = jj & (S_ - 1);
                    outp[(((size_t)(b * H_ + hh) * D_) + d) * S_ + s] =
                        f2bf(acc[mt][nt][r] + bi);
                }
            }
        }
    }
}

// ---------------------------------------------------------------------------
// MFMA attention (R5 skeleton + exp2 + MFMA-denominator + dbuf staging).
// Block = 512 threads = 8 waves; 128 queries/block, 16/wave. TK=64.
// S^T = K.Q^T scoring (C-layout holds 4 consecutive keys/lane). P truncated
// to bf16 via v_perm pack (one op per 2 elems), written as b64 into the
// chunk-swizzled wave-private Pq. Denominator = P x ones-column via MFMA
// (same truncated p values -> truncation bias still cancels); its C-layout
// row = q, so the epilogue needs no shuffles at all. Ks/Vt double-buffered:
// ONE barrier per iter (sync drains prev loads via vmcnt(0), making the
// buf[i^1] overwrite safe). q is pre-scaled by log2(e)/8 -> exp2f here.
// XCD swizzle: bh = (j&7)*4 + (j>>7) keeps each XCD on 4 bh (L2-resident).
// ---------------------------------------------------------------------------
__global__ __launch_bounds__(512, 4) void attn_kernel(
    const unsigned short* __restrict__ Q, const unsigned short* __restrict__ K,
    const unsigned short* __restrict__ V, float* __restrict__ out)
{
    constexpr int TQ = 128, TK = 64;
    __shared__ unsigned short Ks[2][TK * 64];   // 2 x 8 KB, swizzled [key][d]
    __shared__ unsigned short Vt[2][D_ * 64];   // 2 x 8 KB, swizzled [d][key]
    __shared__ unsigned short Pq[TQ * 64];      // 16 KB, wave-private rows

    const int t    = threadIdx.x;
    const int lane = t & 63;
    const int w    = t >> 6;        // wave 0..7
    const int l15  = lane & 15;
    const int quad = lane >> 4;

    const int j    = blockIdx.x;
    const int bh   = (j & 7) * 4 + (j >> 7);
    const int q0   = ((j >> 3) & 15) * TQ;
    const int wq0  = q0 + w * 16;   // this wave's query base

    const unsigned short* Qp = Q + (size_t)bh * S_ * D_;
    const unsigned short* Kp = K + (size_t)bh * S_ * D_;
    const unsigned short* Vp = V + (size_t)bh * D_ * S_;   // [d][s]

    // Q B-operand frags (n = q = l15), pre-scaled by log2(e)/8
    bf16x8 qf[2];
    #pragma unroll
    for (int ks = 0; ks < 2; ++ks)
        qf[ks] = *(const bf16x8*)(Qp + (size_t)(wq0 + l15) * D_ + ks*32 + quad*8);

    bf16x8 ones;
    #pragma unroll
    for (int i = 0; i < 8; ++i) ones[i] = (short)0x3F80;   // bf16 1.0

    f32x4 Oacc[4];
    #pragma unroll
    for (int nt = 0; nt < 4; ++nt)
        #pragma unroll
        for (int r = 0; r < 4; ++r) Oacc[nt][r] = 0.f;
    f32x4 Dacc;
    #pragma unroll
    for (int r = 0; r < 4; ++r) Dacc[r] = 0.f;

    // staging addresses (swizzle-inverse on the global side)
    const int lrow = lane >> 3;                       // 0..7
    const int gch  = ((lane & 7) ^ (lrow & 7)) * 8;   // shorts
    const int srow = w * 8 + lrow;                    // 0..63 (key row / d row)
    const unsigned short* kgp = Kp + (size_t)srow * D_ + gch;
    const unsigned short* vgp = Vp + (size_t)srow * S_ + gch;

    const int swzkey = (l15 & 7) << 1;  // per-q-row chunk XOR key for Pq

    // prologue: stage tile 0 into buffer 0
    gload16(kgp, &Ks[0][t * 8]);
    gload16(vgp, &Vt[0][t * 8]);
    kgp += TK * D_; vgp += TK;

    for (int it = 0; it < S_ / TK; ++it) {
        __syncthreads();   // drains my gloads (vmcnt0+lgkmcnt0) + all waves
        const int cur = it & 1;
        if (it < S_ / TK - 1) {
            gload16(kgp, &Ks[cur ^ 1][t * 8]);
            gload16(vgp, &Vt[cur ^ 1][t * 8]);
            kgp += TK * D_; vgp += TK;
        }
        const unsigned short* KsC = Ks[cur];
        const unsigned short* VtC = Vt[cur];
        const int k0 = it * TK;

        // ---- S^T = K Q^T : 64 keys (4 mt of 16) x 16 q per wave ----
        f32x4 sacc[4];
        #pragma unroll
        for (int mt = 0; mt < 4; ++mt)
            #pragma unroll
            for (int r = 0; r < 4; ++r) sacc[mt][r] = 0.f;
        #pragma unroll
        for (int mt = 0; mt < 4; ++mt) {
            bf16x8 kf0 = *(const bf16x8*)&KsC[SWZ(mt*16 + l15, quad)];
            bf16x8 kf1 = *(const bf16x8*)&KsC[SWZ(mt*16 + l15, 4 + quad)];
            sacc[mt] = __builtin_amdgcn_mfma_f32_16x16x32_bf16(kf0, qf[0], sacc[mt], 0, 0, 0);
            sacc[mt] = __builtin_amdgcn_mfma_f32_16x16x32_bf16(kf1, qf[1], sacc[mt], 0, 0, 0);
        }

        // ---- exp2 + (rare) inverted-window mask; perm-pack b64 P writes ----
        #pragma unroll
        for (int mt = 0; mt < 4; ++mt) {
            const int kt0 = k0 + mt*16;
            const bool band = (unsigned)(wq0 - kt0 + 18) <= 36u;  // wave-uniform
            float p[4];
            if (band) {
                #pragma unroll
                for (int r = 0; r < 4; ++r) {
                    int dlt = (wq0 + l15) - (kt0 + quad*4 + r);
                    if (dlt < 0) dlt = -dlt;
                    p[r] = (dlt <= WIN_) ? 0.f : exp2f(sacc[mt][r]);
                }
            } else {
                #pragma unroll
                for (int r = 0; r < 4; ++r) p[r] = exp2f(sacc[mt][r]);
            }
            union { float f; unsigned int u; } c0, c1, c2, c3;
            c0.f = p[0]; c1.f = p[1]; c2.f = p[2]; c3.f = p[3];
            unsigned int lo = __builtin_amdgcn_perm(c1.u, c0.u, 0x07060302u);
            unsigned int hi = __builtin_amdgcn_perm(c3.u, c2.u, 0x07060302u);
            const int slot = (mt*4 + quad) ^ swzkey;
            *(unsigned long long*)&Pq[(w*16 + l15) * 64 + slot * 4] =
                ((unsigned long long)hi << 32) | lo;
        }
        // no barrier: P rows are wave-private

        // ---- O += P V ; D += P 1 (denominator via MFMA) ----
        #pragma unroll
        for (int ks = 0; ks < 2; ++ks) {
            const int phys = (ks*8 + quad*2) ^ swzkey;   // even -> 16B aligned
            bf16x8 pf = *(const bf16x8*)&Pq[(w*16 + l15) * 64 + phys * 4];
            Dacc = __builtin_amdgcn_mfma_f32_16x16x32_bf16(pf, ones, Dacc, 0, 0, 0);
            #pragma unroll
            for (int nt = 0; nt < 4; ++nt) {
                bf16x8 vf = *(const bf16x8*)&VtC[SWZ(nt*16 + l15, ks*4 + quad)];
                Oacc[nt] = __builtin_amdgcn_mfma_f32_16x16x32_bf16(pf, vf, Oacc[nt], 0, 0, 0);
            }
        }
    }

    // ---- epilogue: Dacc row = q matches Oacc rows exactly; no shuffles ----
    const int b  = bh >> 4;
    const int hh = bh & 15;
    #pragma unroll
    for (int r = 0; r < 4; ++r) {
        const float iv = 1.f / Dacc[r];
        const int qg = wq0 + quad*4 + r;
        float* op = out + (((size_t)b * S_ + qg) * H_ + hh) * D_;
        #pragma unroll
        for (int nt = 0; nt < 4; ++nt)
            op[nt*16 + l15] = Oacc[nt][r] * iv;
    }
}

extern "C" void kernel_launch(void* const* d_in, const int* in_sizes, int n_in,
                              void* d_out, int out_size, void* d_ws, size_t ws_size,
                              hipStream_t stream) {
    const float* x  = (const float*)d_in[0];
    const float* Wq = (const float*)d_in[1];
    const float* bq = (const float*)d_in[2];
    const float* Wk = (const float*)d_in[3];
    const float* bk = (const float*)d_in[4];
    const float* Wv = (const float*)d_in[5];
    const float* bv = (const float*)d_in[6];
    float* out = (float*)d_out;

    const size_t per = (size_t)B_ * H_ * S_ * D_;   // 4,194,304 elements
    const size_t wsz = (size_t)E_ * E_;             // 1,048,576
    unsigned short* qb  = (unsigned short*)d_ws;
    unsigned short* kb  = qb + per;
    unsigned short* vb  = kb + per;
    unsigned short* xbf = vb + per;
    unsigned short* wqb = xbf + per;
    unsigned short* wkb = wqb + wsz;
    unsigned short* wvb = wkb + wsz;

    dim3 cgrid((B_ * S_ * E_ + 2047) / 2048, 4);
    cast_kernel<<<cgrid, 256, 0, stream>>>(x, Wq, Wk, Wv, xbf, wqb, wkb, wvb);

    dim3 ggrid(B_ * S_ / 128, E_ / 128, 3);
    gemm_kernel<<<ggrid, 256, 0, stream>>>(xbf, wqb, wkb, wvb, bq, bk, bv, qb, kb, vb);

    attn_kernel<<<dim3(512), 512, 0, stream>>>(qb, kb, vb, out);
}

// Round 9
// 159.727 us; speedup vs baseline: 1.1841x; 1.1157x over previous
//
#include <hip/hip_runtime.h>
#include <hip/hip_bf16.h>
#include <cstddef>
#include <cstdint>

#define B_ 2
#define S_ 2048
#define E_ 1024
#define H_ 16
#define D_ 64
#define WIN_ 3

using bf16x8 = __attribute__((ext_vector_type(8))) short;  // 8 bf16 = 4 VGPRs
using f32x4  = __attribute__((ext_vector_type(4))) float;  // MFMA C/D

static __device__ __forceinline__ unsigned short f2bf(float f) {
    union { float f; unsigned int u; } c; c.f = f;
    unsigned int r = c.u + 0x7FFF + ((c.u >> 16) & 1);   // round-to-nearest-even
    return (unsigned short)(r >> 16);
}

static __device__ __forceinline__ void gload16(const void* g, void* l) {
    __builtin_amdgcn_global_load_lds(
        (const __attribute__((address_space(1))) void*)g,
        (__attribute__((address_space(3))) void*)l, 16, 0, 0);
}

// XOR-swizzled LDS index (shorts) for [row][chunk-of-8-shorts] tiles with
// 64-short rows: slot = chunk ^ (row & 7). Breaks the 128B-row bank aliasing
// while staying global_load_lds-compatible (lane*16B contiguous).
#define SWZ(row, c) ((((row) * 8) + ((c) ^ ((row) & 7))) * 8)

// ---------------------------------------------------------------------------
// fp32 -> bf16 cast: y=0: x (4M elems), y=1..3: Wq/Wk/Wv (1M each)
// ---------------------------------------------------------------------------
__global__ __launch_bounds__(256) void cast_kernel(
    const float* __restrict__ X,  const float* __restrict__ Wq,
    const float* __restrict__ Wk, const float* __restrict__ Wv,
    unsigned short* __restrict__ xb,  unsigned short* __restrict__ wqb,
    unsigned short* __restrict__ wkb, unsigned short* __restrict__ wvb)
{
    const float* src; unsigned short* dst; int n;
    switch (blockIdx.y) {
        case 0:  src = X;  dst = xb;  n = B_ * S_ * E_; break;
        case 1:  src = Wq; dst = wqb; n = E_ * E_;      break;
        case 2:  src = Wk; dst = wkb; n = E_ * E_;      break;
        default: src = Wv; dst = wvb; n = E_ * E_;      break;
    }
    int i = (blockIdx.x * 256 + threadIdx.x) * 8;
    if (i >= n) return;
    float4 a = *(const float4*)(src + i);
    float4 b = *(const float4*)(src + i + 4);
    ushort4 lo, hi;
    lo.x = f2bf(a.x); lo.y = f2bf(a.y); lo.z = f2bf(a.z); lo.w = f2bf(a.w);
    hi.x = f2bf(b.x); hi.y = f2bf(b.y); hi.z = f2bf(b.z); hi.w = f2bf(b.w);
    *(ushort4*)(dst + i)     = lo;
    *(ushort4*)(dst + i + 4) = hi;
}

// ---------------------------------------------------------------------------
// bf16 MFMA projection GEMM (m97 structure + swizzled LDS):
// C[i,j] = sum_k A[i,k]*B[j,k]; 128x128 tile, BK=64, 4 waves, 4x4 frags.
// z=0: A=x, B=Wq -> q bf16 [B,H,S,D] scaled log2(e)/8 (exp2 softmax path)
// z=1: A=x, B=Wk -> k bf16 [B,H,S,D]
// z=2: A=Wv, B=x (swapped) -> v bf16 [B,H,D,S] with coalesced stores
// ---------------------------------------------------------------------------
__global__ __launch_bounds__(256, 4) void gemm_kernel(
    const unsigned short* __restrict__ xb,
    const unsigned short* __restrict__ wqb, const unsigned short* __restrict__ wkb,
    const unsigned short* __restrict__ wvb,
    const float* __restrict__ bq, const float* __restrict__ bk,
    const float* __restrict__ bv,
    unsigned short* __restrict__ qb, unsigned short* __restrict__ kb,
    unsigned short* __restrict__ vb)
{
    constexpr int BM = 128, BK = 64;
    __shared__ unsigned short As[BM * BK];
    __shared__ unsigned short Bs[BM * BK];

    const int t    = threadIdx.x;
    const int lane = t & 63;
    const int w    = t >> 6;
    const int l15  = lane & 15;
    const int quad = lane >> 4;
    const int wm   = w & 1;
    const int wn   = w >> 1;
    const int m0   = blockIdx.x * BM;
    const int n0   = blockIdx.y * BM;
    const int z    = blockIdx.z;

    const unsigned short *Ab, *Bb; const float* bias; unsigned short* outp;
    int i0, j0; float sc = 1.0f;
    if (z == 0)      { Ab = xb;  Bb = wqb; bias = bq; outp = qb; i0 = m0; j0 = n0;
                       sc = 0.125f * 1.44269504088896f; }
    else if (z == 1) { Ab = xb;  Bb = wkb; bias = bk; outp = kb; i0 = m0; j0 = n0; }
    else             { Ab = wvb; Bb = xb;  bias = bv; outp = vb; i0 = n0; j0 = m0; }

    const int lrow = lane >> 3;
    const int gch  = ((lane & 7) ^ (lrow & 7)) * 8;
    const int lsl  = (lane & 7) * 8;

    f32x4 acc[4][4];
    #pragma unroll
    for (int mt = 0; mt < 4; ++mt)
        #pragma unroll
        for (int nt = 0; nt < 4; ++nt)
            #pragma unroll
            for (int r = 0; r < 4; ++r) acc[mt][nt][r] = 0.f;

    for (int k0 = 0; k0 < E_; k0 += BK) {
        __syncthreads();
        #pragma unroll
        for (int is = 0; is < 4; ++is) {
            int r = (w * 4 + is) * 8 + lrow;
            gload16(Ab + (size_t)(i0 + r) * E_ + k0 + gch, &As[r * BK + lsl]);
            gload16(Bb + (size_t)(j0 + r) * E_ + k0 + gch, &Bs[r * BK + lsl]);
        }
        __syncthreads();

        #pragma unroll
        for (int ks = 0; ks < 2; ++ks) {
            bf16x8 af[4], bfr[4];
            #pragma unroll
            for (int mt = 0; mt < 4; ++mt)
                af[mt] = *(const bf16x8*)&As[SWZ(wm*64 + mt*16 + l15, ks*4 + quad)];
            #pragma unroll
            for (int nt = 0; nt < 4; ++nt)
                bfr[nt] = *(const bf16x8*)&Bs[SWZ(wn*64 + nt*16 + l15, ks*4 + quad)];
            #pragma unroll
            for (int mt = 0; mt < 4; ++mt)
                #pragma unroll
                for (int nt = 0; nt < 4; ++nt)
                    acc[mt][nt] = __builtin_amdgcn_mfma_f32_16x16x32_bf16(
                        af[mt], bfr[nt], acc[mt][nt], 0, 0, 0);
        }
    }

    if (z < 2) {
        float bj[4];
        #pragma unroll
        for (int nt = 0; nt < 4; ++nt) bj[nt] = bias[j0 + wn*64 + nt*16 + l15];
        #pragma unroll
        for (int mt = 0; mt < 4; ++mt) {
            #pragma unroll
            for (int r = 0; r < 4; ++r) {
                int i = i0 + wm*64 + mt*16 + quad*4 + r;
                int b = i >> 11, s = i & (S_ - 1);
                #pragma unroll
                for (int nt = 0; nt < 4; ++nt) {
                    int jj = j0 + wn*64 + nt*16 + l15;
                    int hh = jj >> 6, d = jj & 63;
                    outp[(((size_t)(b * H_ + hh) * S_) + s) * D_ + d] =
                        f2bf((acc[mt][nt][r] + bj[nt]) * sc);
                }
            }
        }
    } else {
        #pragma unroll
        for (int mt = 0; mt < 4; ++mt) {
            #pragma unroll
            for (int r = 0; r < 4; ++r) {
                int i = i0 + wm*64 + mt*16 + quad*4 + r;
                int hh = i >> 6, d = i & 63;
                float bi = bias[i];
                #pragma unroll
                for (int nt = 0; nt < 4; ++nt) {
                    int jj = j0 + wn*64 + nt*16 + l15;
                    int b = jj >> 11, s = jj & (S_ - 1);
                    outp[(((size_t)(b * H_ + hh) * D_) + d) * S_ + s] =
                        f2bf(acc[mt][nt][r] + bi);
                }
            }
        }
    }
}

// ---------------------------------------------------------------------------
// MFMA attention (R5 skeleton + raw-exp2 + MFMA-denominator + dbuf staging).
// Block = 512 threads = 8 waves; 128 queries/block, 16/wave. TK=64.
// S^T = K.Q^T scoring (C-layout holds 4 consecutive keys/lane). P truncated
// to bf16 via v_perm pack, written as b64 into the chunk-swizzled
// wave-private Pq. Denominator = P x ones-column via MFMA (same truncated p
// values -> truncation bias cancels); its C-layout row = q, so the epilogue
// needs no shuffles. Ks/Vt double-buffered: ONE barrier per iter (the sync
// drains this wave's prior global_load_lds via vmcnt(0), making the buf^1
// overwrite safe). q is pre-scaled by log2(e)/8 in gemm ->
// __builtin_amdgcn_exp2f here (bare v_exp_f32; R7's exp2f pulled in OCML
// range handling and cost +10 VALU ops/elem -- the measured 61->70 regression).
// XCD swizzle: bh = (j&7)*4 + (j>>7) keeps each XCD on 4 bh (L2-resident).
// ---------------------------------------------------------------------------
__global__ __launch_bounds__(512, 4) void attn_kernel(
    const unsigned short* __restrict__ Q, const unsigned short* __restrict__ K,
    const unsigned short* __restrict__ V, float* __restrict__ out)
{
    constexpr int TQ = 128, TK = 64;
    __shared__ unsigned short Ks[2][TK * 64];   // 2 x 8 KB, swizzled [key][d]
    __shared__ unsigned short Vt[2][D_ * 64];   // 2 x 8 KB, swizzled [d][key]
    __shared__ unsigned short Pq[TQ * 64];      // 16 KB, wave-private rows

    const int t    = threadIdx.x;
    const int lane = t & 63;
    const int w    = t >> 6;        // wave 0..7
    const int l15  = lane & 15;
    const int quad = lane >> 4;

    const int j    = blockIdx.x;
    const int bh   = (j & 7) * 4 + (j >> 7);
    const int q0   = ((j >> 3) & 15) * TQ;
    const int wq0  = q0 + w * 16;   // this wave's query base

    const unsigned short* Qp = Q + (size_t)bh * S_ * D_;
    const unsigned short* Kp = K + (size_t)bh * S_ * D_;
    const unsigned short* Vp = V + (size_t)bh * D_ * S_;   // [d][s]

    // Q B-operand frags (n = q = l15), pre-scaled by log2(e)/8
    bf16x8 qf[2];
    #pragma unroll
    for (int ks = 0; ks < 2; ++ks)
        qf[ks] = *(const bf16x8*)(Qp + (size_t)(wq0 + l15) * D_ + ks*32 + quad*8);

    bf16x8 ones;
    #pragma unroll
    for (int i = 0; i < 8; ++i) ones[i] = (short)0x3F80;   // bf16 1.0

    f32x4 Oacc[4];
    #pragma unroll
    for (int nt = 0; nt < 4; ++nt)
        #pragma unroll
        for (int r = 0; r < 4; ++r) Oacc[nt][r] = 0.f;
    f32x4 Dacc;
    #pragma unroll
    for (int r = 0; r < 4; ++r) Dacc[r] = 0.f;

    // staging addresses (swizzle-inverse on the global side)
    const int lrow = lane >> 3;                       // 0..7
    const int gch  = ((lane & 7) ^ (lrow & 7)) * 8;   // shorts
    const int srow = w * 8 + lrow;                    // 0..63 (key row / d row)
    const unsigned short* kgp = Kp + (size_t)srow * D_ + gch;
    const unsigned short* vgp = Vp + (size_t)srow * S_ + gch;

    const int swzkey = (l15 & 7) << 1;  // per-q-row chunk XOR key for Pq

    // prologue: stage tile 0 into buffer 0
    gload16(kgp, &Ks[0][t * 8]);
    gload16(vgp, &Vt[0][t * 8]);
    kgp += TK * D_; vgp += TK;

    for (int it = 0; it < S_ / TK; ++it) {
        __syncthreads();   // drains my gloads (vmcnt0+lgkmcnt0) + all waves
        const int cur = it & 1;
        if (it < S_ / TK - 1) {
            gload16(kgp, &Ks[cur ^ 1][t * 8]);
            gload16(vgp, &Vt[cur ^ 1][t * 8]);
            kgp += TK * D_; vgp += TK;
        }
        const unsigned short* KsC = Ks[cur];
        const unsigned short* VtC = Vt[cur];
        const int k0 = it * TK;

        // ---- S^T = K Q^T : 64 keys (4 mt of 16) x 16 q per wave ----
        f32x4 sacc[4];
        #pragma unroll
        for (int mt = 0; mt < 4; ++mt)
            #pragma unroll
            for (int r = 0; r < 4; ++r) sacc[mt][r] = 0.f;
        #pragma unroll
        for (int mt = 0; mt < 4; ++mt) {
            bf16x8 kf0 = *(const bf16x8*)&KsC[SWZ(mt*16 + l15, quad)];
            bf16x8 kf1 = *(const bf16x8*)&KsC[SWZ(mt*16 + l15, 4 + quad)];
            sacc[mt] = __builtin_amdgcn_mfma_f32_16x16x32_bf16(kf0, qf[0], sacc[mt], 0, 0, 0);
            sacc[mt] = __builtin_amdgcn_mfma_f32_16x16x32_bf16(kf1, qf[1], sacc[mt], 0, 0, 0);
        }

        // ---- exp2 + (rare) inverted-window mask; perm-pack b64 P writes ----
        #pragma unroll
        for (int mt = 0; mt < 4; ++mt) {
            const int kt0 = k0 + mt*16;
            const bool band = (unsigned)(wq0 - kt0 + 18) <= 36u;  // wave-uniform
            float p[4];
            if (band) {
                #pragma unroll
                for (int r = 0; r < 4; ++r) {
                    int dlt = (wq0 + l15) - (kt0 + quad*4 + r);
                    if (dlt < 0) dlt = -dlt;
                    p[r] = (dlt <= WIN_) ? 0.f : __builtin_amdgcn_exp2f(sacc[mt][r]);
                }
            } else {
                #pragma unroll
                for (int r = 0; r < 4; ++r) p[r] = __builtin_amdgcn_exp2f(sacc[mt][r]);
            }
            union { float f; unsigned int u; } c0, c1, c2, c3;
            c0.f = p[0]; c1.f = p[1]; c2.f = p[2]; c3.f = p[3];
            unsigned int lo = __builtin_amdgcn_perm(c1.u, c0.u, 0x07060302u);
            unsigned int hi = __builtin_amdgcn_perm(c3.u, c2.u, 0x07060302u);
            const int slot = (mt*4 + quad) ^ swzkey;
            *(unsigned long long*)&Pq[(w*16 + l15) * 64 + slot * 4] =
                ((unsigned long long)hi << 32) | lo;
        }
        // no barrier: P rows are wave-private

        // ---- O += P V ; D += P 1 (denominator via MFMA) ----
        #pragma unroll
        for (int ks = 0; ks < 2; ++ks) {
            const int phys = (ks*8 + quad*2) ^ swzkey;   // even -> 16B aligned
            bf16x8 pf = *(const bf16x8*)&Pq[(w*16 + l15) * 64 + phys * 4];
            Dacc = __builtin_amdgcn_mfma_f32_16x16x32_bf16(pf, ones, Dacc, 0, 0, 0);
            #pragma unroll
            for (int nt = 0; nt < 4; ++nt) {
                bf16x8 vf = *(const bf16x8*)&VtC[SWZ(nt*16 + l15, ks*4 + quad)];
                Oacc[nt] = __builtin_amdgcn_mfma_f32_16x16x32_bf16(pf, vf, Oacc[nt], 0, 0, 0);
            }
        }
    }

    // ---- epilogue: Dacc row = q matches Oacc rows exactly; no shuffles ----
    const int b  = bh >> 4;
    const int hh = bh & 15;
    #pragma unroll
    for (int r = 0; r < 4; ++r) {
        const float iv = 1.f / Dacc[r];
        const int qg = wq0 + quad*4 + r;
        float* op = out + (((size_t)b * S_ + qg) * H_ + hh) * D_;
        #pragma unroll
        for (int nt = 0; nt < 4; ++nt)
            op[nt*16 + l15] = Oacc[nt][r] * iv;
    }
}

extern "C" void kernel_launch(void* const* d_in, const int* in_sizes, int n_in,
                              void* d_out, int out_size, void* d_ws, size_t ws_size,
                              hipStream_t stream) {
    const float* x  = (const float*)d_in[0];
    const float* Wq = (const float*)d_in[1];
    const float* bq = (const float*)d_in[2];
    const float* Wk = (const float*)d_in[3];
    const float* bk = (const float*)d_in[4];
    const float* Wv = (const float*)d_in[5];
    const float* bv = (const float*)d_in[6];
    float* out = (float*)d_out;

    const size_t per = (size_t)B_ * H_ * S_ * D_;   // 4,194,304 elements
    const size_t wsz = (size_t)E_ * E_;             // 1,048,576
    unsigned short* qb  = (unsigned short*)d_ws;
    unsigned short* kb  = qb + per;
    unsigned short* vb  = kb + per;
    unsigned short* xbf = vb + per;
    unsigned short* wqb = xbf + per;
    unsigned short* wkb = wqb + wsz;
    unsigned short* wvb = wkb + wsz;

    dim3 cgrid((B_ * S_ * E_ + 2047) / 2048, 4);
    cast_kernel<<<cgrid, 256, 0, stream>>>(x, Wq, Wk, Wv, xbf, wqb, wkb, wvb);

    dim3 ggrid(B_ * S_ / 128, E_ / 128, 3);
    gemm_kernel<<<ggrid, 256, 0, stream>>>(xbf, wqb, wkb, wvb, bq, bk, bv, qb, kb, vb);

    attn_kernel<<<dim3(512), 512, 0, stream>>>(qb, kb, vb, out);
}

// Round 10
// 157.901 us; speedup vs baseline: 1.1978x; 1.0116x over previous
//
#include <hip/hip_runtime.h>
#include <hip/hip_bf16.h>
#include <cstddef>
#include <cstdint>

#define B_ 2
#define S_ 2048
#define E_ 1024
#define H_ 16
#define D_ 64
#define WIN_ 3

using bf16x8 = __attribute__((ext_vector_type(8))) short;  // 8 bf16 = 4 VGPRs
using f32x4  = __attribute__((ext_vector_type(4))) float;  // MFMA C/D

static __device__ __forceinline__ unsigned short f2bf(float f) {
    union { float f; unsigned int u; } c; c.f = f;
    unsigned int r = c.u + 0x7FFF + ((c.u >> 16) & 1);   // round-to-nearest-even
    return (unsigned short)(r >> 16);
}

static __device__ __forceinline__ void gload16(const void* g, void* l) {
    __builtin_amdgcn_global_load_lds(
        (const __attribute__((address_space(1))) void*)g,
        (__attribute__((address_space(3))) void*)l, 16, 0, 0);
}

// XOR-swizzled LDS index (shorts) for [row][chunk-of-8-shorts] tiles with
// 64-short rows: slot = chunk ^ (row & 7). Breaks the 128B-row bank aliasing
// while staying global_load_lds-compatible (lane*16B contiguous).
#define SWZ(row, c) ((((row) * 8) + ((c) ^ ((row) & 7))) * 8)

// ---------------------------------------------------------------------------
// fp32 -> bf16 cast: y=0: x (4M elems), y=1..3: Wq/Wk/Wv (1M each)
// ---------------------------------------------------------------------------
__global__ __launch_bounds__(256) void cast_kernel(
    const float* __restrict__ X,  const float* __restrict__ Wq,
    const float* __restrict__ Wk, const float* __restrict__ Wv,
    unsigned short* __restrict__ xb,  unsigned short* __restrict__ wqb,
    unsigned short* __restrict__ wkb, unsigned short* __restrict__ wvb)
{
    const float* src; unsigned short* dst; int n;
    switch (blockIdx.y) {
        case 0:  src = X;  dst = xb;  n = B_ * S_ * E_; break;
        case 1:  src = Wq; dst = wqb; n = E_ * E_;      break;
        case 2:  src = Wk; dst = wkb; n = E_ * E_;      break;
        default: src = Wv; dst = wvb; n = E_ * E_;      break;
    }
    int i = (blockIdx.x * 256 + threadIdx.x) * 8;
    if (i >= n) return;
    float4 a = *(const float4*)(src + i);
    float4 b = *(const float4*)(src + i + 4);
    ushort4 lo, hi;
    lo.x = f2bf(a.x); lo.y = f2bf(a.y); lo.z = f2bf(a.z); lo.w = f2bf(a.w);
    hi.x = f2bf(b.x); hi.y = f2bf(b.y); hi.z = f2bf(b.z); hi.w = f2bf(b.w);
    *(ushort4*)(dst + i)     = lo;
    *(ushort4*)(dst + i + 4) = hi;
}

// ---------------------------------------------------------------------------
// bf16 MFMA projection GEMM (m97 structure + swizzled LDS):
// C[i,j] = sum_k A[i,k]*B[j,k]; 128x128 tile, BK=64, 4 waves, 4x4 frags.
// z=0: A=x, B=Wq -> q bf16 [B,H,S,D] scaled log2(e)/8 (exp2 softmax path)
// z=1: A=x, B=Wk -> k bf16 [B,H,S,D]
// z=2: A=Wv, B=x (swapped) -> v bf16 [B,H,D,S] with coalesced stores
// ---------------------------------------------------------------------------
__global__ __launch_bounds__(256, 4) void gemm_kernel(
    const unsigned short* __restrict__ xb,
    const unsigned short* __restrict__ wqb, const unsigned short* __restrict__ wkb,
    const unsigned short* __restrict__ wvb,
    const float* __restrict__ bq, const float* __restrict__ bk,
    const float* __restrict__ bv,
    unsigned short* __restrict__ qb, unsigned short* __restrict__ kb,
    unsigned short* __restrict__ vb)
{
    constexpr int BM = 128, BK = 64;
    __shared__ unsigned short As[BM * BK];
    __shared__ unsigned short Bs[BM * BK];

    const int t    = threadIdx.x;
    const int lane = t & 63;
    const int w    = t >> 6;
    const int l15  = lane & 15;
    const int quad = lane >> 4;
    const int wm   = w & 1;
    const int wn   = w >> 1;
    const int m0   = blockIdx.x * BM;
    const int n0   = blockIdx.y * BM;
    const int z    = blockIdx.z;

    const unsigned short *Ab, *Bb; const float* bias; unsigned short* outp;
    int i0, j0; float sc = 1.0f;
    if (z == 0)      { Ab = xb;  Bb = wqb; bias = bq; outp = qb; i0 = m0; j0 = n0;
                       sc = 0.125f * 1.44269504088896f; }
    else if (z == 1) { Ab = xb;  Bb = wkb; bias = bk; outp = kb; i0 = m0; j0 = n0; }
    else             { Ab = wvb; Bb = xb;  bias = bv; outp = vb; i0 = n0; j0 = m0; }

    const int lrow = lane >> 3;
    const int gch  = ((lane & 7) ^ (lrow & 7)) * 8;
    const int lsl  = (lane & 7) * 8;

    f32x4 acc[4][4];
    #pragma unroll
    for (int mt = 0; mt < 4; ++mt)
        #pragma unroll
        for (int nt = 0; nt < 4; ++nt)
            #pragma unroll
            for (int r = 0; r < 4; ++r) acc[mt][nt][r] = 0.f;

    for (int k0 = 0; k0 < E_; k0 += BK) {
        __syncthreads();
        #pragma unroll
        for (int is = 0; is < 4; ++is) {
            int r = (w * 4 + is) * 8 + lrow;
            gload16(Ab + (size_t)(i0 + r) * E_ + k0 + gch, &As[r * BK + lsl]);
            gload16(Bb + (size_t)(j0 + r) * E_ + k0 + gch, &Bs[r * BK + lsl]);
        }
        __syncthreads();

        #pragma unroll
        for (int ks = 0; ks < 2; ++ks) {
            bf16x8 af[4], bfr[4];
            #pragma unroll
            for (int mt = 0; mt < 4; ++mt)
                af[mt] = *(const bf16x8*)&As[SWZ(wm*64 + mt*16 + l15, ks*4 + quad)];
            #pragma unroll
            for (int nt = 0; nt < 4; ++nt)
                bfr[nt] = *(const bf16x8*)&Bs[SWZ(wn*64 + nt*16 + l15, ks*4 + quad)];
            #pragma unroll
            for (int mt = 0; mt < 4; ++mt)
                #pragma unroll
                for (int nt = 0; nt < 4; ++nt)
                    acc[mt][nt] = __builtin_amdgcn_mfma_f32_16x16x32_bf16(
                        af[mt], bfr[nt], acc[mt][nt], 0, 0, 0);
        }
    }

    if (z < 2) {
        float bj[4];
        #pragma unroll
        for (int nt = 0; nt < 4; ++nt) bj[nt] = bias[j0 + wn*64 + nt*16 + l15];
        #pragma unroll
        for (int mt = 0; mt < 4; ++mt) {
            #pragma unroll
            for (int r = 0; r < 4; ++r) {
                int i = i0 + wm*64 + mt*16 + quad*4 + r;
                int b = i >> 11, s = i & (S_ - 1);
                #pragma unroll
                for (int nt = 0; nt < 4; ++nt) {
                    int jj = j0 + wn*64 + nt*16 + l15;
                    int hh = jj >> 6, d = jj & 63;
                    outp[(((size_t)(b * H_ + hh) * S_) + s) * D_ + d] =
                        f2bf((acc[mt][nt][r] + bj[nt]) * sc);
                }
            }
        }
    } else {
        #pragma unroll
        for (int mt = 0; mt < 4; ++mt) {
            #pragma unroll
            for (int r = 0; r < 4; ++r) {
                int i = i0 + wm*64 + mt*16 + quad*4 + r;
                int hh = i >> 6, d = i & 63;
                float bi = bias[i];
                #pragma unroll
                for (int nt = 0; nt < 4; ++nt) {
                    int jj = j0 + wn*64 + nt*16 + l15;
                    int b = jj >> 11, s = jj & (S_ - 1);
                    outp[(((size_t)(b * H_ + hh) * D_) + d) * S_ + s] =
                        f2bf(acc[mt][nt][r] + bi);
                }
            }
        }
    }
}

// ---------------------------------------------------------------------------
// MFMA attention, key-split revision ("R6 done right"):
// Block = 512 threads = 8 waves = 4 q-groups (32 q as 2x16 tiles) x 2 key
// halves (64 keys). TK=128/iter staged as four 64-wide proven-swizzle arrays
// (Ks0/Ks1/Vt0/Vt1), single-buffered, 2 barriers/iter. All P handling keeps
// the R8 16x16 geometry exactly (C-layout: row=key=quad*4+r, col=q=l15;
// b64 slot-swizzled writes, b128 A-frag reads, wave-private region).
// K/V frag reads now amortize over 2 q-tiles: 20 b128 per 32q*64k wave-iter
// vs R8's 18 per 16q*64k -> 1.6x less LDS-pipe pressure per unit work (the
// measured R8 bottleneck). Denominator via P x ones MFMA (per q-tile).
// Key halves merged once at the epilogue via LDS (Oex aliases Pq, 32 KB).
// q pre-scaled by log2(e)/8 in gemm -> raw v_exp_f32 here.
// XCD swizzle: bh = (j&7)*4 + (j>>7) keeps each XCD on 4 bh (L2-resident).
// ---------------------------------------------------------------------------
__global__ __launch_bounds__(512, 4) void attn_kernel(
    const unsigned short* __restrict__ Q, const unsigned short* __restrict__ K,
    const unsigned short* __restrict__ V, float* __restrict__ out)
{
    constexpr int TQ = 128, TK = 128;
    __shared__ unsigned short Ks0[4096], Ks1[4096];   // keys 0..63 / 64..127, [key][d]
    __shared__ unsigned short Vt0[4096], Vt1[4096];   // [d][key 0..63 / 64..127]
    __shared__ unsigned short Pq[16384];              // 32 KB: 8 x wave-private 32x64
    __shared__ float          Dex[TQ];                // wk=1 denominators

    const int t    = threadIdx.x;
    const int lane = t & 63;
    const int w    = t >> 6;        // wave 0..7
    const int wq   = w & 3;         // q-group (32 rows)
    const int wk   = w >> 2;        // key half
    const int l15  = lane & 15;
    const int quad = lane >> 4;

    const int j    = blockIdx.x;
    const int bh   = (j & 7) * 4 + (j >> 7);
    const int q0   = ((j >> 3) & 15) * TQ;
    const int wq0  = q0 + wq * 32;  // this wave's query base (32 rows)

    const unsigned short* Qp = Q + (size_t)bh * S_ * D_;
    const unsigned short* Kp = K + (size_t)bh * S_ * D_;
    const unsigned short* Vp = V + (size_t)bh * D_ * S_;   // [d][s]

    // Q B-operand frags (n = q = l15), pre-scaled by log2(e)/8: [mt][ks]
    bf16x8 qf[2][2];
    #pragma unroll
    for (int mt = 0; mt < 2; ++mt)
        #pragma unroll
        for (int ks = 0; ks < 2; ++ks)
            qf[mt][ks] = *(const bf16x8*)(Qp + (size_t)(wq0 + mt*16 + l15) * D_
                                          + ks*32 + quad*8);

    bf16x8 ones;
    #pragma unroll
    for (int i = 0; i < 8; ++i) ones[i] = (short)0x3F80;   // bf16 1.0

    f32x4 Oacc[2][4];
    #pragma unroll
    for (int mt = 0; mt < 2; ++mt)
        #pragma unroll
        for (int nt = 0; nt < 4; ++nt)
            #pragma unroll
            for (int r = 0; r < 4; ++r) Oacc[mt][nt][r] = 0.f;
    f32x4 Dacc[2];
    #pragma unroll
    for (int mt = 0; mt < 2; ++mt)
        #pragma unroll
        for (int r = 0; r < 4; ++r) Dacc[mt][r] = 0.f;

    // staging: 512 threads, 1 gload16 per array each; rows 0..63
    const int srow = t >> 3;                          // 0..63
    const int gch  = ((t & 7) ^ (srow & 7)) * 8;      // swizzle-inverse (shorts)
    const unsigned short* kg0 = Kp + (size_t)srow * D_ + gch;          // keys 0..63
    const unsigned short* kg1 = Kp + (size_t)(srow + 64) * D_ + gch;   // keys 64..127
    const unsigned short* vg0 = Vp + (size_t)srow * S_ + gch;
    const unsigned short* vg1 = Vp + (size_t)srow * S_ + 64 + gch;

    const unsigned short* KsW = wk ? Ks1 : Ks0;
    const unsigned short* VtW = wk ? Vt1 : Vt0;
    unsigned short* Pw = &Pq[w * 2048];               // wave-private 32q x 64k
    const int swzkey = (l15 & 7) << 1;                // P chunk swizzle key

    for (int k0 = 0; k0 < S_; k0 += TK) {
        __syncthreads();                 // prior iter done reading Ks/Vt
        gload16(kg0, &Ks0[t * 8]);
        gload16(kg1, &Ks1[t * 8]);
        gload16(vg0, &Vt0[t * 8]);
        gload16(vg1, &Vt1[t * 8]);
        kg0 += TK * D_; kg1 += TK * D_; vg0 += TK; vg1 += TK;
        __syncthreads();                 // staged (compiler drains vmcnt)

        // ---- S^T = K Q^T : 64 keys (4 kt of 16) x 32 q (2 mt) per wave ----
        f32x4 sacc[2][4];
        #pragma unroll
        for (int mt = 0; mt < 2; ++mt)
            #pragma unroll
            for (int kt = 0; kt < 4; ++kt)
                #pragma unroll
                for (int r = 0; r < 4; ++r) sacc[mt][kt][r] = 0.f;
        #pragma unroll
        for (int kt = 0; kt < 4; ++kt) {
            bf16x8 kf0 = *(const bf16x8*)&KsW[SWZ(kt*16 + l15, quad)];
            bf16x8 kf1 = *(const bf16x8*)&KsW[SWZ(kt*16 + l15, 4 + quad)];
            #pragma unroll
            for (int mt = 0; mt < 2; ++mt) {
                sacc[mt][kt] = __builtin_amdgcn_mfma_f32_16x16x32_bf16(
                    kf0, qf[mt][0], sacc[mt][kt], 0, 0, 0);
                sacc[mt][kt] = __builtin_amdgcn_mfma_f32_16x16x32_bf16(
                    kf1, qf[mt][1], sacc[mt][kt], 0, 0, 0);
            }
        }

        // ---- exp2 + (rare) inverted-window mask; perm-pack b64 P writes ----
        #pragma unroll
        for (int mt = 0; mt < 2; ++mt) {
            const int qt0 = wq0 + mt*16;
            #pragma unroll
            for (int kt = 0; kt < 4; ++kt) {
                const int kt0 = k0 + wk*64 + kt*16;
                const bool band = (unsigned)(qt0 - kt0 + 18) <= 36u;  // wave-uniform
                float p[4];
                if (band) {
                    #pragma unroll
                    for (int r = 0; r < 4; ++r) {
                        int dlt = (qt0 + l15) - (kt0 + quad*4 + r);
                        if (dlt < 0) dlt = -dlt;
                        p[r] = (dlt <= WIN_) ? 0.f
                             : __builtin_amdgcn_exp2f(sacc[mt][kt][r]);
                    }
                } else {
                    #pragma unroll
                    for (int r = 0; r < 4; ++r)
                        p[r] = __builtin_amdgcn_exp2f(sacc[mt][kt][r]);
                }
                union { float f; unsigned int u; } c0, c1, c2, c3;
                c0.f = p[0]; c1.f = p[1]; c2.f = p[2]; c3.f = p[3];
                unsigned int lo = __builtin_amdgcn_perm(c1.u, c0.u, 0x07060302u);
                unsigned int hi = __builtin_amdgcn_perm(c3.u, c2.u, 0x07060302u);
                const int slot = (kt*4 + quad) ^ swzkey;
                *(unsigned long long*)&Pw[(mt*16 + l15) * 64 + slot * 4] =
                    ((unsigned long long)hi << 32) | lo;
            }
        }
        // no barrier: P region is wave-private

        // ---- O += P V ; D += P 1 over this wave's key half ----
        #pragma unroll
        for (int ks = 0; ks < 2; ++ks) {
            const int phys = (ks*8 + quad*2) ^ swzkey;   // even -> 16B aligned
            bf16x8 pf[2];
            #pragma unroll
            for (int mt = 0; mt < 2; ++mt) {
                pf[mt] = *(const bf16x8*)&Pw[(mt*16 + l15) * 64 + phys * 4];
                Dacc[mt] = __builtin_amdgcn_mfma_f32_16x16x32_bf16(
                    pf[mt], ones, Dacc[mt], 0, 0, 0);
            }
            #pragma unroll
            for (int nt = 0; nt < 4; ++nt) {
                bf16x8 vf = *(const bf16x8*)&VtW[SWZ(nt*16 + l15, ks*4 + quad)];
                #pragma unroll
                for (int mt = 0; mt < 2; ++mt)
                    Oacc[mt][nt] = __builtin_amdgcn_mfma_f32_16x16x32_bf16(
                        pf[mt], vf, Oacc[mt][nt], 0, 0, 0);
            }
        }
    }

    // ---- merge key halves through LDS (Oex aliases Pq; sizes verified) ----
    __syncthreads();                     // all Pq reads done
    float* Oex = (float*)Pq;             // 8192 floats = 32 KB
    if (wk == 1) {
        #pragma unroll
        for (int mt = 0; mt < 2; ++mt) {
            #pragma unroll
            for (int r = 0; r < 4; ++r) {
                const int qrow = wq*32 + mt*16 + quad*4 + r;
                Dex[qrow] = Dacc[mt][r];             // 16 lanes same value: benign
                #pragma unroll
                for (int nt = 0; nt < 4; ++nt)
                    Oex[qrow * 64 + nt*16 + l15] = Oacc[mt][nt][r];
            }
        }
    }
    __syncthreads();                     // Oex/Dex visible
    if (wk == 0) {
        const int b  = bh >> 4;
        const int hh = bh & 15;
        #pragma unroll
        for (int mt = 0; mt < 2; ++mt) {
            #pragma unroll
            for (int r = 0; r < 4; ++r) {
                const int qrow = wq*32 + mt*16 + quad*4 + r;
                const float iv = 1.f / (Dacc[mt][r] + Dex[qrow]);
                const int qg = q0 + qrow;
                float* op = out + (((size_t)b * S_ + qg) * H_ + hh) * D_;
                #pragma unroll
                for (int nt = 0; nt < 4; ++nt)
                    op[nt*16 + l15] =
                        (Oacc[mt][nt][r] + Oex[qrow * 64 + nt*16 + l15]) * iv;
            }
        }
    }
}

extern "C" void kernel_launch(void* const* d_in, const int* in_sizes, int n_in,
                              void* d_out, int out_size, void* d_ws, size_t ws_size,
                              hipStream_t stream) {
    const float* x  = (const float*)d_in[0];
    const float* Wq = (const float*)d_in[1];
    const float* bq = (const float*)d_in[2];
    const float* Wk = (const float*)d_in[3];
    const float* bk = (const float*)d_in[4];
    const float* Wv = (const float*)d_in[5];
    const float* bv = (const float*)d_in[6];
    float* out = (float*)d_out;

    const size_t per = (size_t)B_ * H_ * S_ * D_;   // 4,194,304 elements
    const size_t wsz = (size_t)E_ * E_;             // 1,048,576
    unsigned short* qb  = (unsigned short*)d_ws;
    unsigned short* kb  = qb + per;
    unsigned short* vb  = kb + per;
    unsigned short* xbf = vb + per;
    unsigned short* wqb = xbf + per;
    unsigned short* wkb = wqb + wsz;
    unsigned short* wvb = wkb + wsz;

    dim3 cgrid((B_ * S_ * E_ + 2047) / 2048, 4);
    cast_kernel<<<cgrid, 256, 0, stream>>>(x, Wq, Wk, Wv, xbf, wqb, wkb, wvb);

    dim3 ggrid(B_ * S_ / 128, E_ / 128, 3);
    gemm_kernel<<<ggrid, 256, 0, stream>>>(xbf, wqb, wkb, wvb, bq, bk, bv, qb, kb, vb);

    attn_kernel<<<dim3(512), 512, 0, stream>>>(qb, kb, vb, out);
}